// Round 4
// baseline (237.768 us; speedup 1.0000x reference)
//
#include <hip/hip_runtime.h>
#include <hip/hip_bf16.h>

// B=32, N=207, T=24, E=128, H=8, d=16, DM=64, M=32
#define Bn 32
#define Nn 207
#define Tt 24
#define Ee 128
#define Hh 8
#define Dm 64
#define Mm 32
#define NBN (Bn * Nn)                // 6624
#define PT ((size_t)Nn * 16384)     // per-tensor Pt fragment elems

typedef __attribute__((ext_vector_type(8))) short bf16x8;
typedef __attribute__((ext_vector_type(4))) float f32x4;

__device__ __forceinline__ unsigned swz256(unsigned a) { return a ^ (((a >> 8) & 7u) << 4); }
__device__ __forceinline__ unsigned swz64(unsigned a)  { return a ^ (((a >> 7) & 3u) << 4); }
__device__ __forceinline__ unsigned f2b(float f) {
  union { float f; unsigned u; } x; x.f = f;
  unsigned u = x.u;
  return ((u + 0x7FFFu + ((u >> 16) & 1u)) >> 16) & 0xFFFFu;
}

// P[n][i][col] = sum_m p1[n*64+i/2][m] * p2[m][(i&1)*128+col] -> bf16 B-fragments:
// Pt[(((n*8+nt)*4+ks)*64 + lane)*8 + j] = P[n][ks*32+(lane>>4)*8+j][nt*16+(lane&15)]
__global__ __launch_bounds__(256) void build_P_frag3(
    const float* __restrict__ qp1, const float* __restrict__ qp2,
    const float* __restrict__ kp1, const float* __restrict__ kp2,
    const float* __restrict__ vp1, const float* __restrict__ vp2,
    unsigned short* __restrict__ Pt) {
  const int tau = blockIdx.y;
  const float* p1 = (tau == 0) ? qp1 : (tau == 1) ? kp1 : vp1;
  const float* p2 = (tau == 0) ? qp2 : (tau == 1) ? kp2 : vp2;
  unsigned short* dst = Pt + (size_t)tau * PT;
  const int bid = blockIdx.x;
  const int n = bid >> 3;
  const int r8 = bid & 7;
  const int ks = r8 >> 1;
  const int chunk = ((r8 & 1) << 1) + (threadIdx.x >> 7);
  const int col = threadIdx.x & 127;
  const int base_i = ks * 32 + chunk * 8;
  const float* p1r = p1 + (size_t)(n * 64 + (base_i >> 1)) * Mm;
  const float* p2a = p2 + col;
  const float* p2b = p2 + 128 + col;
  float acc[8] = {};
#pragma unroll
  for (int m = 0; m < Mm; ++m) {
    float a = p2a[m * 256], b = p2b[m * 256];
#pragma unroll
    for (int jj = 0; jj < 4; ++jj) {
      float pv = p1r[jj * Mm + m];
      acc[2 * jj]     = fmaf(pv, a, acc[2 * jj]);
      acc[2 * jj + 1] = fmaf(pv, b, acc[2 * jj + 1]);
    }
  }
  const int nt = col >> 4;
  const int lane = (chunk << 4) | (col & 15);
  union { unsigned short u[8]; uint4 v; } w;
#pragma unroll
  for (int j = 0; j < 8; ++j) w.u[j] = (unsigned short)f2b(acc[j]);
  *(uint4*)(dst + (size_t)(((n * 8 + nt) * 4 + ks) * 64 + lane) * 8) = w.v;
}

__global__ __launch_bounds__(256) void build_W_frag(const float* __restrict__ W,
                                                    unsigned short* __restrict__ Wt) {
  for (int idx = threadIdx.x; idx < 1024; idx += 256) {
    int lane = idx & 63, ks = (idx >> 6) & 3, nt = idx >> 8;
    union { unsigned short u[8]; uint4 v; } w;
#pragma unroll
    for (int j = 0; j < 8; ++j)
      w.u[j] = (unsigned short)f2b(W[(size_t)(ks * 32 + (lane >> 4) * 8 + j) * 64 + nt * 16 + (lane & 15)]);
    *(uint4*)(Wt + (size_t)idx * 8) = w.v;
  }
}

// One block per (b,n); 4 waves; 32 KB LDS -> 5 blocks/CU.
// Regions: XQ=0 (6K: xq stage -> outh), XK=6144 (6K: xk stage -> xv stage),
//          QS=12288 (6K q-proj) + KS=18432 (6K k-proj) -> probs bf16[8][24][32] swz64 @12288,
//          VST=24576 (8K v-proj transposed [128][32] swz64, s>=24 zeroed).
__global__ __launch_bounds__(256, 5) void fused_attn(
    const float* __restrict__ Qin, const float* __restrict__ Kin,
    const float* __restrict__ Vin,
    const unsigned short* __restrict__ Ptq, const unsigned short* __restrict__ Ptk,
    const unsigned short* __restrict__ Ptv, const unsigned short* __restrict__ Wt,
    const float* __restrict__ bias,
    float* __restrict__ out, float* __restrict__ attn) {
  __shared__ __align__(16) char smem[32768];
  const int tid = threadIdx.x;
  const int lane = tid & 63;
  const int wv = tid >> 6;
  const int c = lane & 15;
  const int g = lane >> 4;
  const f32x4 zf = {0.f, 0.f, 0.f, 0.f};
  const bf16x8 zb = {0, 0, 0, 0, 0, 0, 0, 0};

  int bx = blockIdx.x;
  bx = (bx & 7) * 828 + (bx >> 3);          // bijective XCD swizzle (6624 = 8*828)
  const int n = bx >> 5;
  const int b = bx & 31;
  const size_t xbase = (size_t)(b * Nn + n) * (Tt * Ee);

  // ---- P0: zero VST; stage xq->XQ, xk->XK (bf16, swz256) ----
  {
    uint4 z4 = {0, 0, 0, 0};
    *(uint4*)(smem + 24576 + tid * 32) = z4;
    *(uint4*)(smem + 24576 + tid * 32 + 16) = z4;
    const float* src[2] = {Qin + xbase, Kin + xbase};
#pragma unroll
    for (int w = 0; w < 2; ++w)
#pragma unroll
      for (int it = 0; it < 3; ++it) {
        int e4 = tid + 256 * it;            // 768 float4 = 24x128
        float4 xv = *(const float4*)(src[w] + (size_t)e4 * 4);
        unsigned a = swz256((unsigned)((e4 >> 5) * 256 + (e4 & 31) * 8));
        uint2 pk;
        pk.x = f2b(xv.x) | (f2b(xv.y) << 16);
        pk.y = f2b(xv.z) | (f2b(xv.w) << 16);
        *(uint2*)(smem + w * 6144 + a) = pk;
      }
  }
  __syncthreads();  // (1)

  // ---- P1: proj q -> QS, proj k -> KS; wave wv owns ntiles {2wv,2wv+1} ----
  {
    const unsigned short* Pts[2] = {Ptq, Ptk};
#pragma unroll
    for (int w = 0; w < 2; ++w) {
      const unsigned short* Pf = Pts[w];
      f32x4 acc[2][2] = {{zf, zf}, {zf, zf}};
#pragma unroll
      for (int ks = 0; ks < 4; ++ks) {
        bf16x8 Bf[2], Af[2];
#pragma unroll
        for (int ntl = 0; ntl < 2; ++ntl)
          Bf[ntl] = *(const bf16x8*)(Pf + (size_t)(((n * 8 + (wv * 2 + ntl)) * 4 + ks) * 64 + lane) * 8);
#pragma unroll
        for (int mt = 0; mt < 2; ++mt) {
          int row = mt * 16 + c; row = row < 24 ? row : 23;
          Af[mt] = *(const bf16x8*)(smem + w * 6144 + swz256((unsigned)(row * 256 + ks * 64 + g * 16)));
        }
        __builtin_amdgcn_s_setprio(1);
#pragma unroll
        for (int mt = 0; mt < 2; ++mt)
#pragma unroll
          for (int ntl = 0; ntl < 2; ++ntl)
            acc[mt][ntl] = __builtin_amdgcn_mfma_f32_16x16x32_bf16(Af[mt], Bf[ntl], acc[mt][ntl], 0, 0, 0);
        __builtin_amdgcn_s_setprio(0);
      }
      char* dst = smem + 12288 + w * 6144;
#pragma unroll
      for (int mt = 0; mt < 2; ++mt)
#pragma unroll
        for (int r = 0; r < 4; ++r) {
          int row = mt * 16 + g * 4 + r;
          if (row < 24) {
#pragma unroll
            for (int ntl = 0; ntl < 2; ++ntl) {
              int col = (wv * 2 + ntl) * 16 + c;
              *(unsigned short*)(dst + swz256((unsigned)(row * 256 + col * 2))) =
                  (unsigned short)f2b(fmaxf(acc[mt][ntl][r], 0.f));
            }
          }
        }
    }
  }
  __syncthreads();  // (2) QS/KS ready

  // ---- P2: scores; wave wv owns heads {2wv, 2wv+1}; K-dim d=16, upper half zeroed ----
  f32x4 sc[2][2][2];
#pragma unroll
  for (int hh = 0; hh < 2; ++hh) {
    int h = wv * 2 + hh;
    bf16x8 Aq[2], Bk[2];
#pragma unroll
    for (int mt = 0; mt < 2; ++mt) {
      int row = mt * 16 + c; row = row < 24 ? row : 23;
      Aq[mt] = zb;
      if (lane < 32) Aq[mt] = *(const bf16x8*)(smem + 12288 + swz256((unsigned)(row * 256 + (h * 16 + g * 8) * 2)));
    }
#pragma unroll
    for (int st = 0; st < 2; ++st) {
      int row = st * 16 + c; row = row < 24 ? row : 23;
      Bk[st] = zb;
      if (lane < 32) Bk[st] = *(const bf16x8*)(smem + 18432 + swz256((unsigned)(row * 256 + (h * 16 + g * 8) * 2)));
    }
    __builtin_amdgcn_s_setprio(1);
#pragma unroll
    for (int mt = 0; mt < 2; ++mt)
#pragma unroll
      for (int st = 0; st < 2; ++st)
        sc[hh][mt][st] = __builtin_amdgcn_mfma_f32_16x16x32_bf16(Aq[mt], Bk[st], zf, 0, 0, 0);
    __builtin_amdgcn_s_setprio(0);
  }
  __syncthreads();  // (3) scores LDS reads done -> QS/KS free for probs

  // ---- P3: load+stage xv -> XK region; softmax (no max pass: scores >= 0, bounded)
  //          + attn global write + probs bf16 [8][24][32] swz64 @12288 ----
  {
    float4 xvr[3];
#pragma unroll
    for (int it = 0; it < 3; ++it)
      xvr[it] = *(const float4*)(Vin + xbase + (size_t)(tid + 256 * it) * 4);

    const size_t abase = (size_t)(b * Nn + n) * (Hh * Tt * Tt);
#pragma unroll
    for (int hh = 0; hh < 2; ++hh) {
      int h = wv * 2 + hh;
#pragma unroll
      for (int mt = 0; mt < 2; ++mt)
#pragma unroll
        for (int r = 0; r < 4; ++r) {
          int t = mt * 16 + g * 4 + r;
          float e0 = (c <= t)      ? __expf(sc[hh][mt][0][r] * 0.25f) : 0.f;
          float e1 = (16 + c <= t) ? __expf(sc[hh][mt][1][r] * 0.25f) : 0.f;
          float s2 = e0 + e1;
          s2 += __shfl_xor(s2, 1);
          s2 += __shfl_xor(s2, 2);
          s2 += __shfl_xor(s2, 4);
          s2 += __shfl_xor(s2, 8);
          float inv = 1.0f / s2;
          float p0 = e0 * inv, p1 = e1 * inv;
          if (t < 24) {
            float* ap = attn + abase + (size_t)h * (Tt * Tt) + t * Tt;
            ap[c] = p0;
            if (c < 8) ap[16 + c] = p1;
            char* q = smem + 12288;
            *(unsigned short*)(q + swz64((unsigned)(h * 1536 + t * 64 + c * 2)))        = (unsigned short)f2b(p0);
            *(unsigned short*)(q + swz64((unsigned)(h * 1536 + t * 64 + (16 + c) * 2))) = (unsigned short)f2b(p1);
          }
        }
    }
#pragma unroll
    for (int it = 0; it < 3; ++it) {
      int e4 = tid + 256 * it;
      unsigned a = swz256((unsigned)((e4 >> 5) * 256 + (e4 & 31) * 8));
      uint2 pk;
      pk.x = f2b(xvr[it].x) | (f2b(xvr[it].y) << 16);
      pk.y = f2b(xvr[it].z) | (f2b(xvr[it].w) << 16);
      *(uint2*)(smem + 6144 + a) = pk;
    }
  }
  __syncthreads();  // (4) xv staged, probs ready

  // ---- P4: proj v -> VST (transposed [e][s], relu) ----
  {
    f32x4 acc[2][2] = {{zf, zf}, {zf, zf}};
#pragma unroll
    for (int ks = 0; ks < 4; ++ks) {
      bf16x8 Bf[2], Af[2];
#pragma unroll
      for (int ntl = 0; ntl < 2; ++ntl)
        Bf[ntl] = *(const bf16x8*)(Ptv + (size_t)(((n * 8 + (wv * 2 + ntl)) * 4 + ks) * 64 + lane) * 8);
#pragma unroll
      for (int mt = 0; mt < 2; ++mt) {
        int row = mt * 16 + c; row = row < 24 ? row : 23;
        Af[mt] = *(const bf16x8*)(smem + 6144 + swz256((unsigned)(row * 256 + ks * 64 + g * 16)));
      }
      __builtin_amdgcn_s_setprio(1);
#pragma unroll
      for (int mt = 0; mt < 2; ++mt)
#pragma unroll
        for (int ntl = 0; ntl < 2; ++ntl)
          acc[mt][ntl] = __builtin_amdgcn_mfma_f32_16x16x32_bf16(Af[mt], Bf[ntl], acc[mt][ntl], 0, 0, 0);
      __builtin_amdgcn_s_setprio(0);
    }
#pragma unroll
    for (int mt = 0; mt < 2; ++mt)
#pragma unroll
      for (int r = 0; r < 4; ++r) {
        int srow = mt * 16 + g * 4 + r;
        if (srow < 24) {
#pragma unroll
          for (int ntl = 0; ntl < 2; ++ntl) {
            int dcol = (wv * 2 + ntl) * 16 + c;
            *(unsigned short*)(smem + 24576 + swz64((unsigned)(dcol * 64 + srow * 2))) =
                (unsigned short)f2b(fmaxf(acc[mt][ntl][r], 0.f));
          }
        }
      }
  }
  __syncthreads();  // (5) VST ready

  // ---- P5: PV -> outh (XQ region, bf16 swz256) ----
  {
    f32x4 pv[2][2];
#pragma unroll
    for (int hh = 0; hh < 2; ++hh) {
      int h = wv * 2 + hh;
      bf16x8 Bv = *(const bf16x8*)(smem + 24576 + swz64((unsigned)((h * 16 + c) * 64 + g * 16)));
#pragma unroll
      for (int mt = 0; mt < 2; ++mt) {
        int row = mt * 16 + c; row = row < 24 ? row : 23;
        bf16x8 Ap = *(const bf16x8*)(smem + 12288 + swz64((unsigned)(h * 1536 + row * 64 + g * 16)));
        pv[hh][mt] = __builtin_amdgcn_mfma_f32_16x16x32_bf16(Ap, Bv, zf, 0, 0, 0);
      }
    }
#pragma unroll
    for (int hh = 0; hh < 2; ++hh) {
      int h = wv * 2 + hh;
#pragma unroll
      for (int mt = 0; mt < 2; ++mt)
#pragma unroll
        for (int r = 0; r < 4; ++r) {
          int t = mt * 16 + g * 4 + r;
          if (t < 24)
            *(unsigned short*)(smem + swz256((unsigned)(t * 256 + (h * 16 + c) * 2))) =
                (unsigned short)f2b(pv[hh][mt][r]);
        }
    }
  }
  __syncthreads();  // (6) outh ready

  // ---- P6: out projection (wave wv owns cols wv*16+c) + bias, relu ----
  {
    f32x4 acc2[2] = {zf, zf};
#pragma unroll
    for (int ks = 0; ks < 4; ++ks) {
      bf16x8 Bw = *(const bf16x8*)(Wt + (size_t)((wv * 4 + ks) * 64 + lane) * 8);
      bf16x8 Af[2];
#pragma unroll
      for (int mt = 0; mt < 2; ++mt) {
        int row = mt * 16 + c; row = row < 24 ? row : 23;
        Af[mt] = *(const bf16x8*)(smem + swz256((unsigned)(row * 256 + ks * 64 + g * 16)));
      }
      __builtin_amdgcn_s_setprio(1);
#pragma unroll
      for (int mt = 0; mt < 2; ++mt)
        acc2[mt] = __builtin_amdgcn_mfma_f32_16x16x32_bf16(Af[mt], Bw, acc2[mt], 0, 0, 0);
      __builtin_amdgcn_s_setprio(0);
    }
    int j = wv * 16 + c;
    float bj = bias[j];
    const size_t obase = (size_t)(b * Nn + n) * (Tt * Dm);
#pragma unroll
    for (int mt = 0; mt < 2; ++mt)
#pragma unroll
      for (int r = 0; r < 4; ++r) {
        int t = mt * 16 + g * 4 + r;
        if (t < 24) out[obase + (size_t)t * Dm + j] = fmaxf(acc2[mt][r] + bj, 0.f);
      }
  }
}

extern "C" void kernel_launch(void* const* d_in, const int* in_sizes, int n_in,
                              void* d_out, int out_size, void* d_ws, size_t ws_size,
                              hipStream_t stream) {
  const float* query = (const float*)d_in[0];
  const float* key   = (const float*)d_in[1];
  const float* value = (const float*)d_in[2];
  const float* qp1 = (const float*)d_in[4];
  const float* qp2 = (const float*)d_in[5];
  const float* kp1 = (const float*)d_in[6];
  const float* kp2 = (const float*)d_in[7];
  const float* vp1 = (const float*)d_in[8];
  const float* vp2 = (const float*)d_in[9];
  const float* out_W = (const float*)d_in[10];
  const float* out_b = (const float*)d_in[11];

  unsigned short* Pt  = (unsigned short*)d_ws;        // 3*PT bf16
  unsigned short* Wtf = Pt + 3 * PT;                  // 8192 bf16

  float* out = (float*)d_out;
  float* attn = out + (size_t)NBN * Tt * Dm;

  build_P_frag3<<<dim3(Nn * 8, 3), 256, 0, stream>>>(qp1, qp2, kp1, kp2, vp1, vp2, Pt);
  build_W_frag<<<1, 256, 0, stream>>>(out_W, Wtf);
  fused_attn<<<NBN, 256, 0, stream>>>(query, key, value,
                                      Pt, Pt + PT, Pt + 2 * PT, Wtf,
                                      out_b, out, attn);
}

// Round 5
// 159.160 us; speedup vs baseline: 1.4939x; 1.4939x over previous
//
#include <hip/hip_runtime.h>
#include <hip/hip_bf16.h>

// B=32, N=207, T=24, E=128, H=8, d=16, DM=64, M=32
#define Bn 32
#define Nn 207
#define Tt 24
#define Ee 128
#define Hh 8
#define Dm 64
#define Mm 32
#define NBN (Bn * Nn)                // 6624
#define PT ((size_t)Nn * 16384)     // per-tensor Pt fragment elems

typedef __attribute__((ext_vector_type(8))) short bf16x8;
typedef __attribute__((ext_vector_type(4))) float f32x4;

__device__ __forceinline__ unsigned swz256(unsigned a) { return a ^ (((a >> 8) & 7u) << 4); }
__device__ __forceinline__ unsigned swz64(unsigned a)  { return a ^ (((a >> 7) & 3u) << 4); }
__device__ __forceinline__ unsigned f2b(float f) {
  union { float f; unsigned u; } x; x.f = f;
  unsigned u = x.u;
  return ((u + 0x7FFFu + ((u >> 16) & 1u)) >> 16) & 0xFFFFu;
}

// P[n][i][col] = sum_m p1[n*64+i/2][m] * p2[m][(i&1)*128+col] -> bf16 B-fragments:
// Pt[(((n*8+nt)*4+ks)*64 + lane)*8 + j] = P[n][ks*32+(lane>>4)*8+j][nt*16+(lane&15)]
__global__ __launch_bounds__(256) void build_P_frag3(
    const float* __restrict__ qp1, const float* __restrict__ qp2,
    const float* __restrict__ kp1, const float* __restrict__ kp2,
    const float* __restrict__ vp1, const float* __restrict__ vp2,
    unsigned short* __restrict__ Pt) {
  const int tau = blockIdx.y;
  const float* p1 = (tau == 0) ? qp1 : (tau == 1) ? kp1 : vp1;
  const float* p2 = (tau == 0) ? qp2 : (tau == 1) ? kp2 : vp2;
  unsigned short* dst = Pt + (size_t)tau * PT;
  const int bid = blockIdx.x;
  const int n = bid >> 3;
  const int r8 = bid & 7;
  const int ks = r8 >> 1;
  const int chunk = ((r8 & 1) << 1) + (threadIdx.x >> 7);
  const int col = threadIdx.x & 127;
  const int base_i = ks * 32 + chunk * 8;
  const float* p1r = p1 + (size_t)(n * 64 + (base_i >> 1)) * Mm;
  const float* p2a = p2 + col;
  const float* p2b = p2 + 128 + col;
  float acc[8] = {};
#pragma unroll
  for (int m = 0; m < Mm; ++m) {
    float a = p2a[m * 256], b = p2b[m * 256];
#pragma unroll
    for (int jj = 0; jj < 4; ++jj) {
      float pv = p1r[jj * Mm + m];
      acc[2 * jj]     = fmaf(pv, a, acc[2 * jj]);
      acc[2 * jj + 1] = fmaf(pv, b, acc[2 * jj + 1]);
    }
  }
  const int nt = col >> 4;
  const int lane = (chunk << 4) | (col & 15);
  union { unsigned short u[8]; uint4 v; } w;
#pragma unroll
  for (int j = 0; j < 8; ++j) w.u[j] = (unsigned short)f2b(acc[j]);
  *(uint4*)(dst + (size_t)(((n * 8 + nt) * 4 + ks) * 64 + lane) * 8) = w.v;
}

__global__ __launch_bounds__(256) void build_W_frag(const float* __restrict__ W,
                                                    unsigned short* __restrict__ Wt) {
  for (int idx = threadIdx.x; idx < 1024; idx += 256) {
    int lane = idx & 63, ks = (idx >> 6) & 3, nt = idx >> 8;
    union { unsigned short u[8]; uint4 v; } w;
#pragma unroll
    for (int j = 0; j < 8; ++j)
      w.u[j] = (unsigned short)f2b(W[(size_t)(ks * 32 + (lane >> 4) * 8 + j) * 64 + nt * 16 + (lane & 15)]);
    *(uint4*)(Wt + (size_t)idx * 8) = w.v;
  }
}

// One block per (b,n); 4 waves; 32 KB LDS.
// Regions: XQ=0 (6K: xq stage -> outh), XK=6144 (6K: xk stage -> xv stage),
//          QS=12288 (6K q-proj, pre-scaled 0.25) + KS=18432 (6K k-proj)
//            -> probs bf16[8][24][32] swz64 @12288,
//          VST=24576 (8K v-proj transposed [128][32] swz64, s>=24 zeroed).
// launch_bounds(256,4): 16 waves/CU. NOT 5 -- that forces VGPR<=64 and spills
// the 32-reg sc[] array to scratch (+270 MB HBM traffic, R4 regression).
__global__ __launch_bounds__(256, 4) void fused_attn(
    const float* __restrict__ Qin, const float* __restrict__ Kin,
    const float* __restrict__ Vin,
    const unsigned short* __restrict__ Ptq, const unsigned short* __restrict__ Ptk,
    const unsigned short* __restrict__ Ptv, const unsigned short* __restrict__ Wt,
    const float* __restrict__ bias,
    float* __restrict__ out, float* __restrict__ attn) {
  __shared__ __align__(16) char smem[32768];
  const int tid = threadIdx.x;
  const int lane = tid & 63;
  const int wv = tid >> 6;
  const int c = lane & 15;
  const int g = lane >> 4;
  const f32x4 zf = {0.f, 0.f, 0.f, 0.f};
  const bf16x8 zb = {0, 0, 0, 0, 0, 0, 0, 0};

  int bx = blockIdx.x;
  bx = (bx & 7) * 828 + (bx >> 3);          // bijective XCD swizzle (6624 = 8*828)
  const int n = bx >> 5;
  const int b = bx & 31;
  const size_t xbase = (size_t)(b * Nn + n) * (Tt * Ee);

  // ---- P0: zero VST; stage xq->XQ, xk->XK (bf16, swz256) ----
  {
    uint4 z4 = {0, 0, 0, 0};
    *(uint4*)(smem + 24576 + tid * 32) = z4;
    *(uint4*)(smem + 24576 + tid * 32 + 16) = z4;
    const float* src[2] = {Qin + xbase, Kin + xbase};
#pragma unroll
    for (int w = 0; w < 2; ++w)
#pragma unroll
      for (int it = 0; it < 3; ++it) {
        int e4 = tid + 256 * it;            // 768 float4 = 24x128
        float4 xv = *(const float4*)(src[w] + (size_t)e4 * 4);
        unsigned a = swz256((unsigned)((e4 >> 5) * 256 + (e4 & 31) * 8));
        uint2 pk;
        pk.x = f2b(xv.x) | (f2b(xv.y) << 16);
        pk.y = f2b(xv.z) | (f2b(xv.w) << 16);
        *(uint2*)(smem + w * 6144 + a) = pk;
      }
  }
  __syncthreads();  // (1)

  // ---- P1: proj q -> QS (pre-scaled by 0.25: bf16-exact exponent shift),
  //          proj k -> KS; wave wv owns ntiles {2wv,2wv+1} ----
  {
    const unsigned short* Pts[2] = {Ptq, Ptk};
#pragma unroll
    for (int w = 0; w < 2; ++w) {
      const unsigned short* Pf = Pts[w];
      f32x4 acc[2][2] = {{zf, zf}, {zf, zf}};
#pragma unroll
      for (int ks = 0; ks < 4; ++ks) {
        bf16x8 Bf[2], Af[2];
#pragma unroll
        for (int ntl = 0; ntl < 2; ++ntl)
          Bf[ntl] = *(const bf16x8*)(Pf + (size_t)(((n * 8 + (wv * 2 + ntl)) * 4 + ks) * 64 + lane) * 8);
#pragma unroll
        for (int mt = 0; mt < 2; ++mt) {
          int row = mt * 16 + c; row = row < 24 ? row : 23;
          Af[mt] = *(const bf16x8*)(smem + w * 6144 + swz256((unsigned)(row * 256 + ks * 64 + g * 16)));
        }
        __builtin_amdgcn_s_setprio(1);
#pragma unroll
        for (int mt = 0; mt < 2; ++mt)
#pragma unroll
          for (int ntl = 0; ntl < 2; ++ntl)
            acc[mt][ntl] = __builtin_amdgcn_mfma_f32_16x16x32_bf16(Af[mt], Bf[ntl], acc[mt][ntl], 0, 0, 0);
        __builtin_amdgcn_s_setprio(0);
      }
      const float postscale = (w == 0) ? 0.25f : 1.0f;
      char* dst = smem + 12288 + w * 6144;
#pragma unroll
      for (int mt = 0; mt < 2; ++mt)
#pragma unroll
        for (int r = 0; r < 4; ++r) {
          int row = mt * 16 + g * 4 + r;
          if (row < 24) {
#pragma unroll
            for (int ntl = 0; ntl < 2; ++ntl) {
              int col = (wv * 2 + ntl) * 16 + c;
              *(unsigned short*)(dst + swz256((unsigned)(row * 256 + col * 2))) =
                  (unsigned short)f2b(fmaxf(acc[mt][ntl][r], 0.f) * postscale);
            }
          }
        }
    }
  }

  // prefetch xv into regs: HBM latency hides under P1 tail + P2
  float4 xvr[3];
#pragma unroll
  for (int it = 0; it < 3; ++it)
    xvr[it] = *(const float4*)(Vin + xbase + (size_t)(tid + 256 * it) * 4);
  __syncthreads();  // (2) QS/KS ready

  // ---- P2: scores; wave wv owns heads {2wv, 2wv+1}; K-dim d=16, upper half zeroed ----
  f32x4 sc[2][2][2];
#pragma unroll
  for (int hh = 0; hh < 2; ++hh) {
    int h = wv * 2 + hh;
    bf16x8 Aq[2], Bk[2];
#pragma unroll
    for (int mt = 0; mt < 2; ++mt) {
      int row = mt * 16 + c; row = row < 24 ? row : 23;
      Aq[mt] = zb;
      if (lane < 32) Aq[mt] = *(const bf16x8*)(smem + 12288 + swz256((unsigned)(row * 256 + (h * 16 + g * 8) * 2)));
    }
#pragma unroll
    for (int st = 0; st < 2; ++st) {
      int row = st * 16 + c; row = row < 24 ? row : 23;
      Bk[st] = zb;
      if (lane < 32) Bk[st] = *(const bf16x8*)(smem + 18432 + swz256((unsigned)(row * 256 + (h * 16 + g * 8) * 2)));
    }
    __builtin_amdgcn_s_setprio(1);
#pragma unroll
    for (int mt = 0; mt < 2; ++mt)
#pragma unroll
      for (int st = 0; st < 2; ++st)
        sc[hh][mt][st] = __builtin_amdgcn_mfma_f32_16x16x32_bf16(Aq[mt], Bk[st], zf, 0, 0, 0);
    __builtin_amdgcn_s_setprio(0);
  }
  __syncthreads();  // (3) scores LDS reads done -> QS/KS free for probs

  // ---- P3: softmax (no max pass: scores bounded, q pre-scaled) + attn write
  //          + probs bf16 [8][24][32] swz64 @12288; then stage xv -> XK ----
  {
    const size_t abase = (size_t)(b * Nn + n) * (Hh * Tt * Tt);
#pragma unroll
    for (int hh = 0; hh < 2; ++hh) {
      int h = wv * 2 + hh;
#pragma unroll
      for (int mt = 0; mt < 2; ++mt)
#pragma unroll
        for (int r = 0; r < 4; ++r) {
          int t = mt * 16 + g * 4 + r;
          float e0 = (c <= t)      ? __expf(sc[hh][mt][0][r]) : 0.f;
          float e1 = (16 + c <= t) ? __expf(sc[hh][mt][1][r]) : 0.f;
          float s2 = e0 + e1;
          s2 += __shfl_xor(s2, 1);
          s2 += __shfl_xor(s2, 2);
          s2 += __shfl_xor(s2, 4);
          s2 += __shfl_xor(s2, 8);
          float inv = 1.0f / s2;
          float p0 = e0 * inv, p1 = e1 * inv;
          if (t < 24) {
            float* ap = attn + abase + (size_t)h * (Tt * Tt) + t * Tt;
            ap[c] = p0;
            if (c < 8) ap[16 + c] = p1;
            char* q = smem + 12288;
            *(unsigned short*)(q + swz64((unsigned)(h * 1536 + t * 64 + c * 2)))        = (unsigned short)f2b(p0);
            *(unsigned short*)(q + swz64((unsigned)(h * 1536 + t * 64 + (16 + c) * 2))) = (unsigned short)f2b(p1);
          }
        }
    }
#pragma unroll
    for (int it = 0; it < 3; ++it) {
      int e4 = tid + 256 * it;
      unsigned a = swz256((unsigned)((e4 >> 5) * 256 + (e4 & 31) * 8));
      uint2 pk;
      pk.x = f2b(xvr[it].x) | (f2b(xvr[it].y) << 16);
      pk.y = f2b(xvr[it].z) | (f2b(xvr[it].w) << 16);
      *(uint2*)(smem + 6144 + a) = pk;
    }
  }
  __syncthreads();  // (4) xv staged, probs ready

  // ---- P4: proj v -> VST (transposed [e][s], relu) ----
  {
    f32x4 acc[2][2] = {{zf, zf}, {zf, zf}};
#pragma unroll
    for (int ks = 0; ks < 4; ++ks) {
      bf16x8 Bf[2], Af[2];
#pragma unroll
      for (int ntl = 0; ntl < 2; ++ntl)
        Bf[ntl] = *(const bf16x8*)(Ptv + (size_t)(((n * 8 + (wv * 2 + ntl)) * 4 + ks) * 64 + lane) * 8);
#pragma unroll
      for (int mt = 0; mt < 2; ++mt) {
        int row = mt * 16 + c; row = row < 24 ? row : 23;
        Af[mt] = *(const bf16x8*)(smem + 6144 + swz256((unsigned)(row * 256 + ks * 64 + g * 16)));
      }
      __builtin_amdgcn_s_setprio(1);
#pragma unroll
      for (int mt = 0; mt < 2; ++mt)
#pragma unroll
        for (int ntl = 0; ntl < 2; ++ntl)
          acc[mt][ntl] = __builtin_amdgcn_mfma_f32_16x16x32_bf16(Af[mt], Bf[ntl], acc[mt][ntl], 0, 0, 0);
      __builtin_amdgcn_s_setprio(0);
    }
#pragma unroll
    for (int mt = 0; mt < 2; ++mt)
#pragma unroll
      for (int r = 0; r < 4; ++r) {
        int srow = mt * 16 + g * 4 + r;
        if (srow < 24) {
#pragma unroll
          for (int ntl = 0; ntl < 2; ++ntl) {
            int dcol = (wv * 2 + ntl) * 16 + c;
            *(unsigned short*)(smem + 24576 + swz64((unsigned)(dcol * 64 + srow * 2))) =
                (unsigned short)f2b(fmaxf(acc[mt][ntl][r], 0.f));
          }
        }
      }
  }
  __syncthreads();  // (5) VST ready

  // ---- P5: PV -> outh (XQ region, bf16 swz256) ----
  {
    f32x4 pv[2][2];
#pragma unroll
    for (int hh = 0; hh < 2; ++hh) {
      int h = wv * 2 + hh;
      bf16x8 Bv = *(const bf16x8*)(smem + 24576 + swz64((unsigned)((h * 16 + c) * 64 + g * 16)));
#pragma unroll
      for (int mt = 0; mt < 2; ++mt) {
        int row = mt * 16 + c; row = row < 24 ? row : 23;
        bf16x8 Ap = *(const bf16x8*)(smem + 12288 + swz64((unsigned)(h * 1536 + row * 64 + g * 16)));
        pv[hh][mt] = __builtin_amdgcn_mfma_f32_16x16x32_bf16(Ap, Bv, zf, 0, 0, 0);
      }
    }
#pragma unroll
    for (int hh = 0; hh < 2; ++hh) {
      int h = wv * 2 + hh;
#pragma unroll
      for (int mt = 0; mt < 2; ++mt)
#pragma unroll
        for (int r = 0; r < 4; ++r) {
          int t = mt * 16 + g * 4 + r;
          if (t < 24)
            *(unsigned short*)(smem + swz256((unsigned)(t * 256 + (h * 16 + c) * 2))) =
                (unsigned short)f2b(pv[hh][mt][r]);
        }
    }
  }
  __syncthreads();  // (6) outh ready

  // ---- P6: out projection (wave wv owns cols wv*16+c) + bias, relu ----
  {
    f32x4 acc2[2] = {zf, zf};
#pragma unroll
    for (int ks = 0; ks < 4; ++ks) {
      bf16x8 Bw = *(const bf16x8*)(Wt + (size_t)((wv * 4 + ks) * 64 + lane) * 8);
      bf16x8 Af[2];
#pragma unroll
      for (int mt = 0; mt < 2; ++mt) {
        int row = mt * 16 + c; row = row < 24 ? row : 23;
        Af[mt] = *(const bf16x8*)(smem + swz256((unsigned)(row * 256 + ks * 64 + g * 16)));
      }
      __builtin_amdgcn_s_setprio(1);
#pragma unroll
      for (int mt = 0; mt < 2; ++mt)
        acc2[mt] = __builtin_amdgcn_mfma_f32_16x16x32_bf16(Af[mt], Bw, acc2[mt], 0, 0, 0);
      __builtin_amdgcn_s_setprio(0);
    }
    int j = wv * 16 + c;
    float bj = bias[j];
    const size_t obase = (size_t)(b * Nn + n) * (Tt * Dm);
#pragma unroll
    for (int mt = 0; mt < 2; ++mt)
#pragma unroll
      for (int r = 0; r < 4; ++r) {
        int t = mt * 16 + g * 4 + r;
        if (t < 24) out[obase + (size_t)t * Dm + j] = fmaxf(acc2[mt][r] + bj, 0.f);
      }
  }
}

extern "C" void kernel_launch(void* const* d_in, const int* in_sizes, int n_in,
                              void* d_out, int out_size, void* d_ws, size_t ws_size,
                              hipStream_t stream) {
  const float* query = (const float*)d_in[0];
  const float* key   = (const float*)d_in[1];
  const float* value = (const float*)d_in[2];
  const float* qp1 = (const float*)d_in[4];
  const float* qp2 = (const float*)d_in[5];
  const float* kp1 = (const float*)d_in[6];
  const float* kp2 = (const float*)d_in[7];
  const float* vp1 = (const float*)d_in[8];
  const float* vp2 = (const float*)d_in[9];
  const float* out_W = (const float*)d_in[10];
  const float* out_b = (const float*)d_in[11];

  unsigned short* Pt  = (unsigned short*)d_ws;        // 3*PT bf16
  unsigned short* Wtf = Pt + 3 * PT;                  // 8192 bf16

  float* out = (float*)d_out;
  float* attn = out + (size_t)NBN * Tt * Dm;

  build_P_frag3<<<dim3(Nn * 8, 3), 256, 0, stream>>>(qp1, qp2, kp1, kp2, vp1, vp2, Pt);
  build_W_frag<<<1, 256, 0, stream>>>(out_W, Wtf);
  fused_attn<<<NBN, 256, 0, stream>>>(query, key, value,
                                      Pt, Pt + PT, Pt + 2 * PT, Wtf,
                                      out_b, out, attn);
}